// Round 8
// baseline (3885.643 us; speedup 1.0000x reference)
//
#include <hip/hip_runtime.h>
#include <math.h>

// Problem constants
constexpr int NB  = 1024;   // batch
constexpr int NL  = 96;     // seq len L
constexpr int ND  = 128;    // D
constexpr int NHS = 512;    // hidden
constexpr int NT  = 24;     // timesteps
constexpr int NN  = 128;    // attention dim N
constexpr int NG4 = 4 * NHS; // 2048
constexpr int NK  = ND + NHS; // 640 concat K
constexpr int BL  = NB * NL; // 98304

typedef __attribute__((ext_vector_type(8))) short bf16x8;
typedef __attribute__((ext_vector_type(4))) float f32x4;

static __device__ __forceinline__ unsigned short f2b(float x) {
    union { float f; unsigned u; } v; v.f = x;
    unsigned r = v.u + 0x7fffu + ((v.u >> 16) & 1u);   // RNE
    return (unsigned short)(r >> 16);
}
static __device__ __forceinline__ float b2f(unsigned short s) {
    union { unsigned u; float f; } v; v.u = ((unsigned)s) << 16;
    return v.f;
}

// fast transcendentals: exp2-based, inf-safe saturation
constexpr float LOG2E  = 1.4426950408889634f;
static __device__ __forceinline__ float fast_exp(float x) {
    return __builtin_amdgcn_exp2f(x * LOG2E);
}
static __device__ __forceinline__ float fast_tanh(float x) {
    float e2 = __builtin_amdgcn_exp2f(x * (2.0f * LOG2E));   // e^{2x}
    return 1.0f - 2.0f * __builtin_amdgcn_rcpf(1.0f + e2);
}
static __device__ __forceinline__ float fast_sigmoid(float x) {
    float e = __builtin_amdgcn_exp2f(-x * LOG2E);
    return __builtin_amdgcn_rcpf(1.0f + e);
}

// ---- light producer/consumer sync (device-scope, monotone counters) ----
static __device__ __forceinline__ void wait_flag(unsigned* f, unsigned target) {
    if (threadIdx.x == 0) {
        while (__hip_atomic_load(f, __ATOMIC_ACQUIRE, __HIP_MEMORY_SCOPE_AGENT) < target)
            __builtin_amdgcn_s_sleep(1);
    }
    __syncthreads();
}
static __device__ __forceinline__ void signal_flag(unsigned* f) {
    __threadfence();
    __syncthreads();
    if (threadIdx.x == 0)
        __hip_atomic_fetch_add(f, 1u, __ATOMIC_RELEASE, __HIP_MEMORY_SCOPE_AGENT);
}

// ---------------------------------------------------------------- init state (+flag zeroing)
__global__ __launch_bounds__(256) void k_init(const float* __restrict__ emb,
                                              const float* __restrict__ y0,
                                              float* __restrict__ c,
                                              unsigned short* __restrict__ Ab0,
                                              float* __restrict__ y,
                                              unsigned* __restrict__ flags) {
    int idx = blockIdx.x * blockDim.x + threadIdx.x;
    if (blockIdx.x == 0 && threadIdx.x < 64) flags[threadIdx.x] = 0;
    if (idx < NB * NHS) {
        int b = idx / NHS, s = idx - b * NHS;
        Ab0[(size_t)b * NK + ND + s] = f2b(emb[b * 2 * NHS + s]);
        c[idx] = emb[b * 2 * NHS + NHS + s];
    }
    if (idx < NB) y[idx] = y0[idx];
}

// ---------------------------------------------------------------- H -> bf16
__global__ __launch_bounds__(256) void k_prep(const float* __restrict__ H,
                                              unsigned short* __restrict__ Hbf) {
    int idx = (blockIdx.x * 256 + threadIdx.x) * 8;
    float4 a = *(const float4*)(H + idx);
    float4 b = *(const float4*)(H + idx + 4);
    bf16x8 o;
    o[0] = (short)f2b(a.x); o[1] = (short)f2b(a.y);
    o[2] = (short)f2b(a.z); o[3] = (short)f2b(a.w);
    o[4] = (short)f2b(b.x); o[5] = (short)f2b(b.y);
    o[6] = (short)f2b(b.z); o[7] = (short)f2b(b.w);
    *(bf16x8*)(Hbf + idx) = o;
}

// ---------------------------------------------------------------- Wa -> bf16, [t][n][d] layout
__global__ __launch_bounds__(128) void k_prepwa(const float* __restrict__ Wa,
                                                unsigned short* __restrict__ Wab) {
    int tn = blockIdx.x;          // t*NN + n
    int t = tn / NN, n = tn - t * NN;
    int d = threadIdx.x;
    Wab[(size_t)tn * ND + d] = f2b(Wa[(size_t)d * (NT * NN) + t * NN + n]);
}

// ---------------------------------------------------------------- W,U -> bf16 Wg[t][kb][n][64]
__global__ __launch_bounds__(256) void k_prepw(const float* __restrict__ W,
                                               const float* __restrict__ U,
                                               unsigned short* __restrict__ Wg) {
    __shared__ unsigned short ts[64][66];
    int nc = blockIdx.x;    // 0..31
    int kc = blockIdx.y;    // 0..9  (= kb)
    int t  = blockIdx.z;    // 0..23
    int tid = threadIdx.x;
    int rowt = tid >> 4;         // 0..15
    int n4   = (tid & 15) << 2;  // 0..60 step 4
#pragma unroll
    for (int i = 0; i < 4; ++i) {
        int kl = i * 16 + rowt;
        int k  = kc * 64 + kl;
        const float* src = (k < ND) ? (W + (size_t)k * (NT * NG4))
                                    : (U + (size_t)(k - ND) * (NT * NG4));
        float4 v = *(const float4*)&src[t * NG4 + nc * 64 + n4];
        ts[kl][n4 + 0] = f2b(v.x);
        ts[kl][n4 + 1] = f2b(v.y);
        ts[kl][n4 + 2] = f2b(v.z);
        ts[kl][n4 + 3] = f2b(v.w);
    }
    __syncthreads();
    size_t base = (((size_t)t * 10 + kc) * NG4 + nc * 64) * 64;
#pragma unroll
    for (int p = 0; p < 2; ++p) {
        int flat = p * 256 + tid;
        int nl = flat >> 3, k8 = (flat & 7) << 3;
        bf16x8 o;
#pragma unroll
        for (int j = 0; j < 8; ++j) o[j] = (short)ts[k8 + j][nl];
        *(bf16x8*)&Wg[base + (size_t)nl * 64 + k8] = o;
    }
}

// ---------------------------------------------------------------- step-0 cua partials
// cua_part[b][p][n] = sum_{k in p-th 64-chunk} c[b,k] * Ua[k,0,n]   (p = 0..7)
__global__ __launch_bounds__(256) void k_cua0(const float* __restrict__ c,
                                              const float* __restrict__ Ua,
                                              float* __restrict__ cua_part) {
    __shared__ float cs[16][64];
    int m0 = blockIdx.x * 16, n0 = blockIdx.y;   // grid (64, 8)
    int tid = threadIdx.x;
#pragma unroll
    for (int i = 0; i < 4; ++i) {
        int idx = tid + i * 256;
        int row = idx >> 6, k = idx & 63;
        cs[row][k] = c[(size_t)(m0 + row) * NHS + n0 * 64 + k];
    }
    __syncthreads();
    int n = tid & 127, bg = tid >> 7;   // bg 0/1 -> 8 rows each
    float a8[8] = {0, 0, 0, 0, 0, 0, 0, 0};
    for (int k = 0; k < 64; ++k) {
        float ua = Ua[(size_t)(n0 * 64 + k) * (NT * NN) + n];  // t = 0
#pragma unroll
        for (int i = 0; i < 8; ++i) a8[i] += cs[bg * 8 + i][k] * ua;
    }
#pragma unroll
    for (int i = 0; i < 8; ++i)
        cua_part[((size_t)(m0 + bg * 8 + i) * 8 + n0) * 128 + n] = a8[i];
}

// ---------------------------------------------------------------- persistent sequence kernel (flag sync)
// 256 blocks x 512 threads (1/CU, all co-resident).
// Per t: attention for 4 batches (b0 = blk*4) -> af[rg] signal;
//        gates+cell for rows m0=(blk>>3)*32, cols n0=blk&7 (64 s) after af wait -> gf[rg] signal.
__global__ __launch_bounds__(512) void k_seq2(
        const unsigned short* __restrict__ Hbf,
        const unsigned short* __restrict__ Wab,
        const float* __restrict__ Va,
        const float* __restrict__ ba,
        const float* __restrict__ bias,
        const float* __restrict__ Wy,
        const float* __restrict__ fcw,
        const float* __restrict__ fcb,
        const float* __restrict__ Ua,
        const unsigned short* __restrict__ Wg,
        const float* __restrict__ c_in,
        float* __restrict__ y_st,
        float* __restrict__ y_part,
        float* __restrict__ cua_part,
        unsigned short* __restrict__ Ab0,
        unsigned short* __restrict__ Ab1,
        float* __restrict__ out_y,
        float* __restrict__ out_h,
        unsigned* __restrict__ af,
        unsigned* __restrict__ gf) {
    __shared__ __align__(16) char pool[34816];   // Ws bf16[128][136]  |  gs f32[4][32][68]
    __shared__ float c_lds[32][68];              // block-private c slice (persistent)
    __shared__ float cua_s4[4][NN];
    __shared__ float sc4[4][NL];

    int tid = threadIdx.x, blk = blockIdx.x;
    int lane = tid & 63, wave = tid >> 6;
    int ln = lane & 15, kg = lane >> 4;
    int b0 = blk * 4;                       // attention batches
    int m0 = (blk >> 3) * 32, n0 = blk & 7; // gates rows / col-chunk
    int rg = blk >> 3;                      // row-group id (shared by both roles)
    const float scale_c = 0.044194173824159216f;  // 1/sqrt(512)
    f32x4 zero = {0.f, 0.f, 0.f, 0.f};

    // load private c slice once
#pragma unroll
    for (int i = 0; i < 4; ++i) {
        int idx = tid + i * 512;
        int row = idx >> 6, s = idx & 63;
        c_lds[row][s] = c_in[(size_t)(m0 + row) * NHS + n0 * 64 + s];
    }

    for (int t = 0; t < NT; ++t) {
        unsigned short* AbC = (t & 1) ? Ab1 : Ab0;
        unsigned short* AbN = (t & 1) ? Ab0 : Ab1;

        // ================= attention (4 batches) =================
        if (t > 0) wait_flag(&gf[rg], 8u * t);

        unsigned short* Ws = (unsigned short*)pool;   // [128][136]
        const unsigned short* src = Wab + (size_t)t * NN * ND;
#pragma unroll
        for (int f = 0; f < 4; ++f) {
            int idx = tid + f * 512;
            int n = idx >> 4, d0 = (idx & 15) << 3;
            *(bf16x8*)&Ws[n * 136 + d0] = *(const bf16x8*)(src + n * ND + d0);
        }
        {
            int bl = tid >> 7, n = tid & 127;
            const float* cp = cua_part + (size_t)(b0 + bl) * 8 * 128 + n;
            float s = ba[t * NN + n];
#pragma unroll
            for (int p = 0; p < 8; ++p) s += cp[p * 128];
            cua_s4[bl][n] = s;
        }
        if (t > 0 && tid < 4) {
            int b = b0 + tid;
            const float* yp = y_part + (size_t)b * 8;
            float yv = fcb[t - 1];
#pragma unroll
            for (int p = 0; p < 8; ++p) yv += yp[p];
            y_st[b] = yv;
            out_y[b * NT + (t - 1)] = yv;
        }
        __syncthreads();

        {   // MFMA scores: 8 waves x 3 tiles = 24 tiles (4 b x 6)
            float va_l[8];
#pragma unroll
            for (int nt = 0; nt < 8; ++nt) va_l[nt] = Va[(nt * 16 + ln) * NT + t];
#pragma unroll
            for (int ti = 0; ti < 3; ++ti) {
                int tau = wave + ti * 8;
                int bl = tau / 6, r0 = (tau % 6) * 16;
                const unsigned short* Hrow = Hbf + ((size_t)(b0 + bl) * NL + r0 + ln) * ND;
                f32x4 acc[8];
#pragma unroll
                for (int nt = 0; nt < 8; ++nt) acc[nt] = zero;
#pragma unroll
                for (int kc = 0; kc < 4; ++kc) {
                    int d0 = kc * 32 + kg * 8;
                    bf16x8 a = *(const bf16x8*)(Hrow + d0);
#pragma unroll
                    for (int nt = 0; nt < 8; ++nt) {
                        bf16x8 bb = *(const bf16x8*)&Ws[(nt * 16 + ln) * 136 + d0];
                        acc[nt] = __builtin_amdgcn_mfma_f32_16x16x32_bf16(a, bb, acc[nt], 0, 0, 0);
                    }
                }
#pragma unroll
                for (int r = 0; r < 4; ++r) {
                    float s = 0.f;
#pragma unroll
                    for (int nt = 0; nt < 8; ++nt) {
                        float pre = acc[nt][r] + cua_s4[bl][nt * 16 + ln];
                        s += va_l[nt] * fast_tanh(pre);
                    }
#pragma unroll
                    for (int off = 1; off < 16; off <<= 1) s += __shfl_xor(s, off);
                    if (ln == 0) sc4[bl][r0 + kg * 4 + r] = s * scale_c;
                }
            }
        }
        __syncthreads();

        if (wave < 4) {   // softmax for b_local = wave
            float s0 = sc4[wave][lane];
            float s1 = (lane < 32) ? sc4[wave][64 + lane] : -1e30f;
            float m = fmaxf(s0, s1);
#pragma unroll
            for (int off = 32; off; off >>= 1) m = fmaxf(m, __shfl_xor(m, off));
            float p0 = fast_exp(s0 - m);
            float p1 = (lane < 32) ? fast_exp(s1 - m) : 0.f;
            float ssum = p0 + p1;
#pragma unroll
            for (int off = 32; off; off >>= 1) ssum += __shfl_xor(ssum, off);
            float inv = __builtin_amdgcn_rcpf(ssum);
            sc4[wave][lane] = p0 * inv;
            if (lane < 32) sc4[wave][64 + lane] = p1 * inv;
        }
        __syncthreads();

        {   // context: one thread per (b_local, d)
            int bl = tid >> 7, dd = tid & 127;
            const unsigned short* Hb = Hbf + (size_t)(b0 + bl) * NL * ND;
            float a0 = 0.f;
            for (int l = 0; l < NL; ++l)
                a0 += sc4[bl][l] * b2f(Hb[(size_t)l * ND + dd]);
            AbC[(size_t)(b0 + bl) * NK + dd] = f2b(a0);
        }
        signal_flag(&af[rg]);

        // ================= gates GEMM + cell (32 rows x 64 s) =================
        wait_flag(&af[rg], 8u * (t + 1));
        {
            int g = wave >> 1, hf = wave & 1;
            int cb = g * NHS + n0 * 64 + hf * 32;
            const unsigned short* A0 = AbC + (size_t)(m0 + ln) * NK;
            const unsigned short* A1 = AbC + (size_t)(m0 + 16 + ln) * NK;
            f32x4 acc[2][2];
#pragma unroll
            for (int rt = 0; rt < 2; ++rt)
#pragma unroll
                for (int nt = 0; nt < 2; ++nt) acc[rt][nt] = zero;

            for (int kb = 0; kb < 10; ++kb) {
                const unsigned short* Wkb = Wg + ((size_t)(t * 10 + kb) * NG4) * 64;
#pragma unroll
                for (int kc = 0; kc < 2; ++kc) {
                    int d0 = kc * 32 + kg * 8;
                    bf16x8 a0 = *(const bf16x8*)(A0 + kb * 64 + d0);
                    bf16x8 a1 = *(const bf16x8*)(A1 + kb * 64 + d0);
#pragma unroll
                    for (int nt = 0; nt < 2; ++nt) {
                        bf16x8 bb = *(const bf16x8*)(Wkb + (size_t)(cb + nt * 16 + ln) * 64 + d0);
                        acc[0][nt] = __builtin_amdgcn_mfma_f32_16x16x32_bf16(a0, bb, acc[0][nt], 0, 0, 0);
                        acc[1][nt] = __builtin_amdgcn_mfma_f32_16x16x32_bf16(a1, bb, acc[1][nt], 0, 0, 0);
                    }
                }
            }
            float* gs = (float*)pool;   // [4][32][68]
#pragma unroll
            for (int rt = 0; rt < 2; ++rt)
#pragma unroll
                for (int nt = 0; nt < 2; ++nt)
#pragma unroll
                    for (int r = 0; r < 4; ++r)
                        gs[(g * 32 + rt * 16 + kg * 4 + r) * 68 + hf * 32 + nt * 16 + ln]
                            = acc[rt][nt][r];
            __syncthreads();

            // cell update: thread -> s_loc (64), 4 rows
            int s_loc = tid & 63, rg4 = tid >> 6;
            int s_glob = n0 * 64 + s_loc;
            float bi0 = bias[t * NG4 + s_glob];
            float bi1 = bias[t * NG4 + NHS + s_glob];
            float bi2 = bias[t * NG4 + 2 * NHS + s_glob];
            float bi3 = bias[t * NG4 + 3 * NHS + s_glob];
            float wy0 = Wy[t * NG4 + s_glob];
            float wy1 = Wy[t * NG4 + NHS + s_glob];
            float wy2 = Wy[t * NG4 + 2 * NHS + s_glob];
            float wy3 = Wy[t * NG4 + 3 * NHS + s_glob];
            float fw  = fcw[t * NHS + s_glob];
#pragma unroll
            for (int i = 0; i < 4; ++i) {
                int row = rg4 * 4 + i;
                int b = m0 + row;
                float yp = y_st[b];
                float gi  = gs[(0 * 32 + row) * 68 + s_loc] + bi0 + yp * wy0;
                float gfv = gs[(1 * 32 + row) * 68 + s_loc] + bi1 + yp * wy1;
                float gg2 = gs[(2 * 32 + row) * 68 + s_loc] + bi2 + yp * wy2;
                float go  = gs[(3 * 32 + row) * 68 + s_loc] + bi3 + yp * wy3;
                float iv = fast_sigmoid(gi);
                float fv = fast_sigmoid(gfv);
                float gv = fast_tanh(gg2);
                float ov = fast_sigmoid(go);
                float cn = fv * c_lds[row][s_loc] + iv * gv;
                float hn = ov * fast_tanh(cn);
                c_lds[row][s_loc] = cn;
                AbN[(size_t)b * NK + ND + s_glob] = f2b(hn);
                out_h[(size_t)b * (NT * NHS) + t * NHS + s_glob] = hn;
                float v = hn * fw;
#pragma unroll
                for (int off = 32; off; off >>= 1) v += __shfl_xor(v, off);
                if (lane == 0) y_part[(size_t)b * 8 + n0] = v;
            }
            __syncthreads();

            // cua partial for t+1 over this block's 64 c-cols
            if (t + 1 < NT) {
                int n = tid & 127, bg = tid >> 7;   // 4 groups x 8 rows
                float a8[8] = {0, 0, 0, 0, 0, 0, 0, 0};
                for (int k = 0; k < 64; ++k) {
                    float ua = Ua[(size_t)(n0 * 64 + k) * (NT * NN) + (t + 1) * NN + n];
#pragma unroll
                    for (int i = 0; i < 8; ++i) a8[i] += c_lds[bg * 8 + i][k] * ua;
                }
#pragma unroll
                for (int i = 0; i < 8; ++i)
                    cua_part[((size_t)(m0 + bg * 8 + i) * 8 + n0) * 128 + n] = a8[i];
            }
        }
        signal_flag(&gf[rg]);
    }

    // final y (t = NT-1)
    wait_flag(&gf[rg], 8u * NT);
    if (tid < 4) {
        int b = b0 + tid;
        const float* yp = y_part + (size_t)b * 8;
        float yv = fcb[NT - 1];
#pragma unroll
        for (int p = 0; p < 8; ++p) yv += yp[p];
        out_y[b * NT + (NT - 1)] = yv;
    }
}

// ---------------------------------------------------------------- launcher
extern "C" void kernel_launch(void* const* d_in, const int* in_sizes, int n_in,
                              void* d_out, int out_size, void* d_ws, size_t ws_size,
                              hipStream_t stream) {
    (void)in_sizes; (void)n_in; (void)out_size; (void)ws_size;
    const float* H    = (const float*)d_in[0];
    const float* y0   = (const float*)d_in[1];
    const float* emb  = (const float*)d_in[2];
    const float* Wa   = (const float*)d_in[4];
    const float* Ua   = (const float*)d_in[5];
    const float* ba   = (const float*)d_in[6];
    const float* Va   = (const float*)d_in[7];
    const float* W    = (const float*)d_in[8];
    const float* U    = (const float*)d_in[9];
    const float* bias = (const float*)d_in[10];
    const float* Wy   = (const float*)d_in[11];
    const float* fcw  = (const float*)d_in[12];
    const float* fcb  = (const float*)d_in[13];

    float* out_y = (float*)d_out;              // (B, T)
    float* out_h = out_y + NB * NT;            // (B, T, HS)

    unsigned* flags = (unsigned*)d_ws;                      // af[32] | gf[32]
    float* ws       = (float*)d_ws + 64;
    float* c_st     = ws;                                   // B*HS
    float* y_st     = c_st + NB * NHS;                      // B
    float* y_part   = y_st + NB;                            // B*8
    float* cua_part = y_part + NB * 8;                      // B*8*128
    unsigned short* Hbf = (unsigned short*)(cua_part + NB * 8 * 128);  // BL*D
    unsigned short* Wab = Hbf + (size_t)BL * ND;            // T*N*D
    unsigned short* Ab0 = Wab + (size_t)NT * NN * ND;       // B*640
    unsigned short* Ab1 = Ab0 + (size_t)NB * NK;            // B*640
    unsigned short* Wg  = Ab1 + (size_t)NB * NK;            // T*10*2048*64

    unsigned* af = flags;
    unsigned* gf = flags + 32;

    hipLaunchKernelGGL(k_init, dim3((NB * NHS) / 256), dim3(256), 0, stream,
                       emb, y0, c_st, Ab0, y_st, flags);
    hipLaunchKernelGGL(k_prep, dim3(BL * ND / (256 * 8)), dim3(256), 0, stream, H, Hbf);
    hipLaunchKernelGGL(k_prepwa, dim3(NT * NN), dim3(128), 0, stream, Wa, Wab);
    hipLaunchKernelGGL(k_prepw, dim3(32, 10, 24), dim3(256), 0, stream, W, U, Wg);
    hipLaunchKernelGGL(k_cua0, dim3(64, 8), dim3(256), 0, stream, c_st, Ua, cua_part);

    void* args[] = {
        (void*)&Hbf, (void*)&Wab, (void*)&Va, (void*)&ba, (void*)&bias,
        (void*)&Wy, (void*)&fcw, (void*)&fcb, (void*)&Ua, (void*)&Wg,
        (void*)&c_st, (void*)&y_st, (void*)&y_part, (void*)&cua_part,
        (void*)&Ab0, (void*)&Ab1, (void*)&out_y, (void*)&out_h,
        (void*)&af, (void*)&gf
    };
    hipLaunchKernelGGL(k_seq2, dim3(256), dim3(512), 0, stream,
                       Hbf, Wab, Va, ba, bias, Wy, fcw, fcb, Ua, Wg,
                       c_st, y_st, y_part, cua_part, Ab0, Ab1, out_y, out_h, af, gf);
    (void)args;
}

// Round 9
// 3679.563 us; speedup vs baseline: 1.0560x; 1.0560x over previous
//
#include <hip/hip_runtime.h>
#include <math.h>

// Problem constants
constexpr int NB  = 1024;   // batch
constexpr int NL  = 96;     // seq len L
constexpr int ND  = 128;    // D
constexpr int NHS = 512;    // hidden
constexpr int NT  = 24;     // timesteps
constexpr int NN  = 128;    // attention dim N
constexpr int NG4 = 4 * NHS; // 2048
constexpr int NK  = ND + NHS; // 640 concat K
constexpr int BL  = NB * NL; // 98304

typedef __attribute__((ext_vector_type(8))) short bf16x8;
typedef __attribute__((ext_vector_type(4))) float f32x4;

static __device__ __forceinline__ unsigned short f2b(float x) {
    union { float f; unsigned u; } v; v.f = x;
    unsigned r = v.u + 0x7fffu + ((v.u >> 16) & 1u);   // RNE
    return (unsigned short)(r >> 16);
}
static __device__ __forceinline__ float b2f(unsigned short s) {
    union { unsigned u; float f; } v; v.u = ((unsigned)s) << 16;
    return v.f;
}

constexpr float LOG2E  = 1.4426950408889634f;
static __device__ __forceinline__ float fast_exp(float x) {
    return __builtin_amdgcn_exp2f(x * LOG2E);
}
static __device__ __forceinline__ float fast_tanh(float x) {
    float e2 = __builtin_amdgcn_exp2f(x * (2.0f * LOG2E));   // e^{2x}
    return 1.0f - 2.0f * __builtin_amdgcn_rcpf(1.0f + e2);
}
static __device__ __forceinline__ float fast_sigmoid(float x) {
    float e = __builtin_amdgcn_exp2f(-x * LOG2E);
    return __builtin_amdgcn_rcpf(1.0f + e);
}

// ---------------------------------------------------------------- H -> bf16
__global__ __launch_bounds__(256) void k_prep(const float* __restrict__ H,
                                              unsigned short* __restrict__ Hbf) {
    int idx = (blockIdx.x * 256 + threadIdx.x) * 8;
    float4 a = *(const float4*)(H + idx);
    float4 b = *(const float4*)(H + idx + 4);
    bf16x8 o;
    o[0] = (short)f2b(a.x); o[1] = (short)f2b(a.y);
    o[2] = (short)f2b(a.z); o[3] = (short)f2b(a.w);
    o[4] = (short)f2b(b.x); o[5] = (short)f2b(b.y);
    o[6] = (short)f2b(b.z); o[7] = (short)f2b(b.w);
    *(bf16x8*)(Hbf + idx) = o;
}

// ---------------------------------------------------------------- Wa -> bf16, [t][n][d]
__global__ __launch_bounds__(128) void k_prepwa(const float* __restrict__ Wa,
                                                unsigned short* __restrict__ Wab) {
    int tn = blockIdx.x;          // t*NN + n
    int t = tn / NN, n = tn - t * NN;
    int d = threadIdx.x;
    Wab[(size_t)tn * ND + d] = f2b(Wa[(size_t)d * (NT * NN) + t * NN + n]);
}

// ---------------------------------------------------------------- Ua -> bf16, [t][n][k=512]
__global__ __launch_bounds__(128) void k_prepua(const float* __restrict__ Ua,
                                                unsigned short* __restrict__ Uab) {
    int tn = blockIdx.x;          // t*NN + n
    int t = tn / NN, n = tn - t * NN;
    int d = threadIdx.x;
#pragma unroll
    for (int j = 0; j < 4; ++j) {
        int k = j * 128 + d;
        Uab[(size_t)tn * NHS + k] = f2b(Ua[(size_t)k * (NT * NN) + t * NN + n]);
    }
}

// ---------------------------------------------------------------- W,U -> bf16 Wg[t][kb][n][64]
__global__ __launch_bounds__(256) void k_prepw(const float* __restrict__ W,
                                               const float* __restrict__ U,
                                               unsigned short* __restrict__ Wg) {
    __shared__ unsigned short ts[64][66];
    int nc = blockIdx.x;    // 0..31
    int kc = blockIdx.y;    // 0..9
    int t  = blockIdx.z;    // 0..23
    int tid = threadIdx.x;
    int rowt = tid >> 4;
    int n4   = (tid & 15) << 2;
#pragma unroll
    for (int i = 0; i < 4; ++i) {
        int kl = i * 16 + rowt;
        int k  = kc * 64 + kl;
        const float* src = (k < ND) ? (W + (size_t)k * (NT * NG4))
                                    : (U + (size_t)(k - ND) * (NT * NG4));
        float4 v = *(const float4*)&src[t * NG4 + nc * 64 + n4];
        ts[kl][n4 + 0] = f2b(v.x);
        ts[kl][n4 + 1] = f2b(v.y);
        ts[kl][n4 + 2] = f2b(v.z);
        ts[kl][n4 + 3] = f2b(v.w);
    }
    __syncthreads();
    size_t base = (((size_t)t * 10 + kc) * NG4 + nc * 64) * 64;
#pragma unroll
    for (int p = 0; p < 2; ++p) {
        int flat = p * 256 + tid;
        int nl = flat >> 3, k8 = (flat & 7) << 3;
        bf16x8 o;
#pragma unroll
        for (int j = 0; j < 8; ++j) o[j] = (short)ts[k8 + j][nl];
        *(bf16x8*)&Wg[base + (size_t)nl * 64 + k8] = o;
    }
}

// ---------------------------------------------------------------- block-autonomous full-sequence kernel
// grid 64 x 1024 threads (16 waves). Block owns batches b0..b0+15 for ALL t:
// state (c, cb, [ht|h], y) lives in LDS; no cross-block communication at all.
__global__ __launch_bounds__(1024) void k_step(
        const unsigned short* __restrict__ Hbf,
        const unsigned short* __restrict__ Wab,   // [t][n][d]
        const unsigned short* __restrict__ Uab,   // [t][n][k]
        const unsigned short* __restrict__ Wg,    // [t][kb][n][64]
        const float* __restrict__ emb,
        const float* __restrict__ y0,
        const float* __restrict__ Va,
        const float* __restrict__ ba,
        const float* __restrict__ bias,
        const float* __restrict__ Wy,
        const float* __restrict__ fcw,
        const float* __restrict__ fcb,
        float* __restrict__ out_y,
        float* __restrict__ out_h) {
    __shared__ float c_lds[16][512];                 // 32 KB   c (f32 master)
    __shared__ unsigned short cb[16][520];           // 16.6 KB c (bf16, MFMA A)
    __shared__ unsigned short ab[16][648];           // 20.7 KB [ht | h] bf16 (MFMA A)
    __shared__ float cua_s[16][NN];                  // 8 KB
    __shared__ float sc[16][NL];                     // 6 KB
    __shared__ float y_lds[16];
    __shared__ float ypar[16][2];
    __shared__ __align__(16) char pool[66048];       // Ws bf16[128][136] | gs8 f32[8][2064]

    int tid = threadIdx.x;
    int lane = tid & 63, wave = tid >> 6;
    int ln = lane & 15, kg = lane >> 4;
    int b0 = blockIdx.x * 16;
    const float scale_c = 0.044194173824159216f;     // 1/sqrt(512)
    f32x4 zero = {0.f, 0.f, 0.f, 0.f};

    // ---- init state from emb / y0 ----
#pragma unroll
    for (int i = 0; i < 8; ++i) {
        int idx = tid + i * 1024;
        int b = idx >> 9, s = idx & 511;
        float cv = emb[(size_t)(b0 + b) * 1024 + 512 + s];
        float hv = emb[(size_t)(b0 + b) * 1024 + s];
        c_lds[b][s] = cv;
        cb[b][s] = f2b(cv);
        ab[b][ND + s] = f2b(hv);
    }
    if (tid < 16) y_lds[tid] = y0[b0 + tid];
    __syncthreads();

    for (int t = 0; t < NT; ++t) {
        // ===== phase 0: cua (waves 0-7, MFMA) + Wa[t] stage (waves 8-15) =====
        unsigned short* Ws = (unsigned short*)pool;
        if (wave < 8) {
            int j = wave;                            // n-tile
            const unsigned short* Ub = Uab + ((size_t)t * NN + j * 16 + ln) * NHS;
            f32x4 acc = zero;
#pragma unroll
            for (int ks = 0; ks < 16; ++ks) {
                bf16x8 a = *(const bf16x8*)&cb[ln][ks * 32 + kg * 8];
                bf16x8 bb = *(const bf16x8*)(Ub + ks * 32 + kg * 8);
                acc = __builtin_amdgcn_mfma_f32_16x16x32_bf16(a, bb, acc, 0, 0, 0);
            }
#pragma unroll
            for (int r = 0; r < 4; ++r) {
                int n = j * 16 + ln;
                cua_s[kg * 4 + r][n] = acc[r] + ba[t * NN + n];
            }
        } else {
            int tid2 = tid - 512;
            const unsigned short* src = Wab + (size_t)t * NN * ND;
#pragma unroll
            for (int f = 0; f < 4; ++f) {
                int c = tid2 + f * 512;
                int n = c >> 4, d0 = (c & 15) << 3;
                *(bf16x8*)&Ws[n * 136 + d0] = *(const bf16x8*)(src + n * ND + d0);
            }
        }
        __syncthreads();

        // ===== phase 1: scores (96 tiles / 16 waves) =====
        {
            float va_l[8];
#pragma unroll
            for (int nt = 0; nt < 8; ++nt) va_l[nt] = Va[(nt * 16 + ln) * NT + t];
#pragma unroll
            for (int i = 0; i < 6; ++i) {
                int tau = i * 16 + wave;
                int bl = tau / 6, rt = tau % 6;
                const unsigned short* Hrow = Hbf + ((size_t)(b0 + bl) * NL + rt * 16 + ln) * ND;
                f32x4 acc[8];
#pragma unroll
                for (int nt = 0; nt < 8; ++nt) acc[nt] = zero;
#pragma unroll
                for (int kc = 0; kc < 4; ++kc) {
                    int d0 = kc * 32 + kg * 8;
                    bf16x8 a = *(const bf16x8*)(Hrow + d0);
#pragma unroll
                    for (int nt = 0; nt < 8; ++nt) {
                        bf16x8 bb = *(const bf16x8*)&Ws[(nt * 16 + ln) * 136 + d0];
                        acc[nt] = __builtin_amdgcn_mfma_f32_16x16x32_bf16(a, bb, acc[nt], 0, 0, 0);
                    }
                }
#pragma unroll
                for (int r = 0; r < 4; ++r) {
                    float s = 0.f;
#pragma unroll
                    for (int nt = 0; nt < 8; ++nt) {
                        float pre = acc[nt][r] + cua_s[bl][nt * 16 + ln];
                        s += va_l[nt] * fast_tanh(pre);
                    }
#pragma unroll
                    for (int off = 1; off < 16; off <<= 1) s += __shfl_xor(s, off);
                    if (ln == 0) sc[bl][rt * 16 + kg * 4 + r] = s * scale_c;
                }
            }
        }
        __syncthreads();

        // ===== phase 2: softmax (wave w -> batch w) =====
        {
            float s0 = sc[wave][lane];
            float s1 = (lane < 32) ? sc[wave][64 + lane] : -1e30f;
            float m = fmaxf(s0, s1);
#pragma unroll
            for (int off = 32; off; off >>= 1) m = fmaxf(m, __shfl_xor(m, off));
            float p0 = fast_exp(s0 - m);
            float p1 = (lane < 32) ? fast_exp(s1 - m) : 0.f;
            float ssum = p0 + p1;
#pragma unroll
            for (int off = 32; off; off >>= 1) ssum += __shfl_xor(ssum, off);
            float inv = __builtin_amdgcn_rcpf(ssum);
            sc[wave][lane] = p0 * inv;
            if (lane < 32) sc[wave][64 + lane] = p1 * inv;
        }
        __syncthreads();

        // ===== phase 3: context -> ab[b][0:128] (wave w -> batch w; 4-way l-split) =====
        {
            int bl = wave, dc = (lane >> 2) & 15, ls = lane & 3;
            int d0 = dc * 8;
            const unsigned short* Hb = Hbf + (size_t)(b0 + bl) * NL * ND;
            float a8[8] = {0, 0, 0, 0, 0, 0, 0, 0};
#pragma unroll
            for (int i = 0; i < 24; ++i) {
                int l = ls * 24 + i;
                bf16x8 hv = *(const bf16x8*)(Hb + (size_t)l * ND + d0);
                float w = sc[bl][l];
#pragma unroll
                for (int j = 0; j < 8; ++j) a8[j] += w * b2f((unsigned short)hv[j]);
            }
#pragma unroll
            for (int j = 0; j < 8; ++j) {
                a8[j] += __shfl_xor(a8[j], 1);
                a8[j] += __shfl_xor(a8[j], 2);
            }
            if (ls == 0) {
                bf16x8 o;
#pragma unroll
                for (int j = 0; j < 8; ++j) o[j] = (short)f2b(a8[j]);
                *(bf16x8*)&ab[bl][d0] = o;
            }
        }
        __syncthreads();

        // ===== phase 4: gates MFMA (wave owns 128 cols) =====
        f32x4 acc[8];
#pragma unroll
        for (int nt = 0; nt < 8; ++nt) acc[nt] = zero;
        {
            int cbase = wave * 128;
            for (int kb = 0; kb < 10; ++kb) {
                const unsigned short* Wkb = Wg + ((size_t)(t * 10 + kb) * NG4) * 64;
#pragma unroll
                for (int kc = 0; kc < 2; ++kc) {
                    int dk = kb * 64 + kc * 32 + kg * 8;
                    bf16x8 a = *(const bf16x8*)&ab[ln][dk];
#pragma unroll
                    for (int nt = 0; nt < 8; ++nt) {
                        bf16x8 bb = *(const bf16x8*)(Wkb
                            + (size_t)(cbase + nt * 16 + ln) * 64 + kc * 32 + kg * 8);
                        acc[nt] = __builtin_amdgcn_mfma_f32_16x16x32_bf16(a, bb, acc[nt], 0, 0, 0);
                    }
                }
            }
        }
        __syncthreads();   // all MFMA A-reads done before pool reuse (gs8)

        // ===== phase 5: cell update in two 8-row halves =====
        float* gs8 = (float*)pool;                    // [8][2064]
#pragma unroll
        for (int h2 = 0; h2 < 2; ++h2) {
            int r0 = h2 * 8;
            if ((kg >> 1) == h2) {
#pragma unroll
                for (int nt = 0; nt < 8; ++nt)
#pragma unroll
                    for (int r = 0; r < 4; ++r) {
                        int row = kg * 4 + r;
                        gs8[(size_t)(row & 7) * 2064 + wave * 128 + nt * 16 + ln]
                            = acc[nt][r];
                    }
            }
            __syncthreads();

            int rloc = tid >> 7, sb = tid & 127;
            int row = r0 + rloc;
            float yp = y_lds[row];
            float ypart = 0.f;
#pragma unroll
            for (int j = 0; j < 4; ++j) {
                int s = sb + j * 128;
                float gi  = gs8[(size_t)rloc * 2064 + s]
                          + bias[t * NG4 + s] + yp * Wy[t * NG4 + s];
                float gfv = gs8[(size_t)rloc * 2064 + 512 + s]
                          + bias[t * NG4 + NHS + s] + yp * Wy[t * NG4 + NHS + s];
                float gg2 = gs8[(size_t)rloc * 2064 + 1024 + s]
                          + bias[t * NG4 + 2 * NHS + s] + yp * Wy[t * NG4 + 2 * NHS + s];
                float go  = gs8[(size_t)rloc * 2064 + 1536 + s]
                          + bias[t * NG4 + 3 * NHS + s] + yp * Wy[t * NG4 + 3 * NHS + s];
                float iv = fast_sigmoid(gi);
                float fv = fast_sigmoid(gfv);
                float gv = fast_tanh(gg2);
                float ov = fast_sigmoid(go);
                float cn = fv * c_lds[row][s] + iv * gv;
                float hn = ov * fast_tanh(cn);
                c_lds[row][s] = cn;
                cb[row][s] = f2b(cn);
                ab[row][ND + s] = f2b(hn);
                out_h[(size_t)(b0 + row) * (NT * NHS) + t * NHS + s] = hn;
                ypart += hn * fcw[t * NHS + s];
            }
#pragma unroll
            for (int off = 32; off; off >>= 1) ypart += __shfl_xor(ypart, off);
            if (lane == 0) ypar[row][(tid >> 6) & 1] = ypart;
            __syncthreads();
        }

        if (tid < 16) {
            float yv = fcb[t] + ypar[tid][0] + ypar[tid][1];
            y_lds[tid] = yv;
            out_y[(b0 + tid) * NT + t] = yv;
        }
        __syncthreads();
    }
}

// ---------------------------------------------------------------- launcher
extern "C" void kernel_launch(void* const* d_in, const int* in_sizes, int n_in,
                              void* d_out, int out_size, void* d_ws, size_t ws_size,
                              hipStream_t stream) {
    (void)in_sizes; (void)n_in; (void)out_size; (void)ws_size;
    const float* H    = (const float*)d_in[0];
    const float* y0   = (const float*)d_in[1];
    const float* emb  = (const float*)d_in[2];
    const float* Wa   = (const float*)d_in[4];
    const float* Ua   = (const float*)d_in[5];
    const float* ba   = (const float*)d_in[6];
    const float* Va   = (const float*)d_in[7];
    const float* W    = (const float*)d_in[8];
    const float* U    = (const float*)d_in[9];
    const float* bias = (const float*)d_in[10];
    const float* Wy   = (const float*)d_in[11];
    const float* fcw  = (const float*)d_in[12];
    const float* fcb  = (const float*)d_in[13];

    float* out_y = (float*)d_out;              // (B, T)
    float* out_h = out_y + NB * NT;            // (B, T, HS)

    unsigned short* Hbf = (unsigned short*)d_ws;            // BL*ND
    unsigned short* Wab = Hbf + (size_t)BL * ND;            // NT*NN*ND
    unsigned short* Uab = Wab + (size_t)NT * NN * ND;       // NT*NN*NHS
    unsigned short* Wg  = Uab + (size_t)NT * NN * NHS;      // NT*10*2048*64

    hipLaunchKernelGGL(k_prep, dim3(BL * ND / (256 * 8)), dim3(256), 0, stream, H, Hbf);
    hipLaunchKernelGGL(k_prepwa, dim3(NT * NN), dim3(128), 0, stream, Wa, Wab);
    hipLaunchKernelGGL(k_prepua, dim3(NT * NN), dim3(128), 0, stream, Ua, Uab);
    hipLaunchKernelGGL(k_prepw, dim3(32, 10, 24), dim3(256), 0, stream, W, U, Wg);

    hipLaunchKernelGGL(k_step, dim3(NB / 16), dim3(1024), 0, stream,
                       Hbf, Wab, Uab, Wg, emb, y0, Va, ba, bias, Wy, fcw, fcb,
                       out_y, out_h);
}

// Round 10
// 1413.185 us; speedup vs baseline: 2.7496x; 2.6037x over previous
//
#include <hip/hip_runtime.h>
#include <math.h>

// Problem constants
constexpr int NB  = 1024;   // batch
constexpr int NL  = 96;     // seq len L
constexpr int ND  = 128;    // D
constexpr int NHS = 512;    // hidden
constexpr int NT  = 24;     // timesteps
constexpr int NN  = 128;    // attention dim N
constexpr int NG4 = 4 * NHS; // 2048
constexpr int NK  = ND + NHS; // 640 concat K
constexpr int BL  = NB * NL; // 98304

typedef __attribute__((ext_vector_type(8))) short bf16x8;
typedef __attribute__((ext_vector_type(4))) float f32x4;

static __device__ __forceinline__ unsigned short f2b(float x) {
    union { float f; unsigned u; } v; v.f = x;
    unsigned r = v.u + 0x7fffu + ((v.u >> 16) & 1u);   // RNE
    return (unsigned short)(r >> 16);
}
static __device__ __forceinline__ float b2f(unsigned short s) {
    union { unsigned u; float f; } v; v.u = ((unsigned)s) << 16;
    return v.f;
}

// fast transcendentals: exp2-based, inf-safe saturation
constexpr float LOG2E  = 1.4426950408889634f;
static __device__ __forceinline__ float fast_exp(float x) {
    return __builtin_amdgcn_exp2f(x * LOG2E);
}
static __device__ __forceinline__ float fast_tanh(float x) {
    float e2 = __builtin_amdgcn_exp2f(x * (2.0f * LOG2E));   // e^{2x}
    return 1.0f - 2.0f * __builtin_amdgcn_rcpf(1.0f + e2);
}
static __device__ __forceinline__ float fast_sigmoid(float x) {
    float e = __builtin_amdgcn_exp2f(-x * LOG2E);
    return __builtin_amdgcn_rcpf(1.0f + e);
}

// ---------------------------------------------------------------- init state
__global__ __launch_bounds__(256) void k_init(const float* __restrict__ emb,
                                              const float* __restrict__ y0,
                                              float* __restrict__ c,
                                              unsigned short* __restrict__ Ab0,
                                              float* __restrict__ y) {
    int idx = blockIdx.x * blockDim.x + threadIdx.x;
    if (idx < NB * NHS) {
        int b = idx / NHS, s = idx - b * NHS;
        Ab0[(size_t)b * NK + ND + s] = f2b(emb[b * 2 * NHS + s]);
        c[idx] = emb[b * 2 * NHS + NHS + s];
    }
    if (idx < NB) y[idx] = y0[idx];
}

// ---------------------------------------------------------------- H -> bf16
__global__ __launch_bounds__(256) void k_prep(const float* __restrict__ H,
                                              unsigned short* __restrict__ Hbf) {
    int idx = (blockIdx.x * 256 + threadIdx.x) * 8;
    float4 a = *(const float4*)(H + idx);
    float4 b = *(const float4*)(H + idx + 4);
    bf16x8 o;
    o[0] = (short)f2b(a.x); o[1] = (short)f2b(a.y);
    o[2] = (short)f2b(a.z); o[3] = (short)f2b(a.w);
    o[4] = (short)f2b(b.x); o[5] = (short)f2b(b.y);
    o[6] = (short)f2b(b.z); o[7] = (short)f2b(b.w);
    *(bf16x8*)(Hbf + idx) = o;
}

// ---------------------------------------------------------------- Wa -> bf16, [t][n][d]
__global__ __launch_bounds__(128) void k_prepwa(const float* __restrict__ Wa,
                                                unsigned short* __restrict__ Wab) {
    int tn = blockIdx.x;          // t*NN + n
    int t = tn / NN, n = tn - t * NN;
    int d = threadIdx.x;
    Wab[(size_t)tn * ND + d] = f2b(Wa[(size_t)d * (NT * NN) + t * NN + n]);
}

// ---------------------------------------------------------------- W,U -> bf16 Wg[t][kb][n][64]
__global__ __launch_bounds__(256) void k_prepw(const float* __restrict__ W,
                                               const float* __restrict__ U,
                                               unsigned short* __restrict__ Wg) {
    __shared__ unsigned short ts[64][66];
    int nc = blockIdx.x;    // 0..31
    int kc = blockIdx.y;    // 0..9
    int t  = blockIdx.z;    // 0..23
    int tid = threadIdx.x;
    int rowt = tid >> 4;
    int n4   = (tid & 15) << 2;
#pragma unroll
    for (int i = 0; i < 4; ++i) {
        int kl = i * 16 + rowt;
        int k  = kc * 64 + kl;
        const float* src = (k < ND) ? (W + (size_t)k * (NT * NG4))
                                    : (U + (size_t)(k - ND) * (NT * NG4));
        float4 v = *(const float4*)&src[t * NG4 + nc * 64 + n4];
        ts[kl][n4 + 0] = f2b(v.x);
        ts[kl][n4 + 1] = f2b(v.y);
        ts[kl][n4 + 2] = f2b(v.z);
        ts[kl][n4 + 3] = f2b(v.w);
    }
    __syncthreads();
    size_t base = (((size_t)t * 10 + kc) * NG4 + nc * 64) * 64;
#pragma unroll
    for (int p = 0; p < 2; ++p) {
        int flat = p * 256 + tid;
        int nl = flat >> 3, k8 = (flat & 7) << 3;
        bf16x8 o;
#pragma unroll
        for (int j = 0; j < 8; ++j) o[j] = (short)ts[k8 + j][nl];
        *(bf16x8*)&Wg[base + (size_t)nl * 64 + k8] = o;
    }
}

// ---------------------------------------------------------------- step-0 cua partials
// cua_part[b][p][n] = sum_{k in p-th 64-chunk} c[b,k] * Ua[k,0,n]   (p = 0..7)
__global__ __launch_bounds__(256) void k_cua0(const float* __restrict__ c,
                                              const float* __restrict__ Ua,
                                              float* __restrict__ cua_part) {
    __shared__ float cs[16][64];
    int m0 = blockIdx.x * 16, n0 = blockIdx.y;   // grid (64, 8)
    int tid = threadIdx.x;
#pragma unroll
    for (int i = 0; i < 4; ++i) {
        int idx = tid + i * 256;
        int row = idx >> 6, k = idx & 63;
        cs[row][k] = c[(size_t)(m0 + row) * NHS + n0 * 64 + k];
    }
    __syncthreads();
    int n = tid & 127, bg = tid >> 7;   // bg 0/1 -> 8 rows each
    float a8[8] = {0, 0, 0, 0, 0, 0, 0, 0};
    for (int k = 0; k < 64; ++k) {
        float ua = Ua[(size_t)(n0 * 64 + k) * (NT * NN) + n];  // t = 0
#pragma unroll
        for (int i = 0; i < 8; ++i) a8[i] += cs[bg * 8 + i][k] * ua;
    }
#pragma unroll
    for (int i = 0; i < 8; ++i)
        cua_part[((size_t)(m0 + bg * 8 + i) * 8 + n0) * 128 + n] = a8[i];
}

// ---------------------------------------------------------------- fused attention (4 batches / block)
// grid 256 x 512 thr. Ws staged once per 4 batches; 8 waves x 3 score tiles.
__global__ __launch_bounds__(512, 2) void k_attn4(
        const unsigned short* __restrict__ Hbf,
        const unsigned short* __restrict__ Wab,
        const float* __restrict__ Va,
        const float* __restrict__ ba,
        const float* __restrict__ cua_part,
        const float* __restrict__ fcb,
        const float* __restrict__ y_part,
        float* __restrict__ y_st,
        float* __restrict__ out_y,
        unsigned short* __restrict__ Ab,     // ping buffer for step t
        int t) {
    __shared__ unsigned short Ws[NN * 136];  // 34.8 KB
    __shared__ float sc4[4][NL];
    __shared__ float cua_s4[4][NN];
    __shared__ float red[4][8][ND];          // 16 KB
    int tid = threadIdx.x;
    int lane = tid & 63, wave = tid >> 6;
    int ln = lane & 15, kg = lane >> 4;
    int b0 = blockIdx.x * 4;
    f32x4 zero = {0.f, 0.f, 0.f, 0.f};

    // stage Wa[t]
    const unsigned short* src = Wab + (size_t)t * NN * ND;
#pragma unroll
    for (int f = 0; f < 4; ++f) {
        int idx = tid + f * 512;
        int n = idx >> 4, d0 = (idx & 15) << 3;
        *(bf16x8*)&Ws[n * 136 + d0] = *(const bf16x8*)(src + n * ND + d0);
    }
    // cua partial sum (+ba)
    {
        int bl = tid >> 7, n = tid & 127;
        const float* cp = cua_part + (size_t)(b0 + bl) * 8 * 128 + n;
        float s = ba[t * NN + n];
#pragma unroll
        for (int p = 0; p < 8; ++p) s += cp[p * 128];
        cua_s4[bl][n] = s;
    }
    // finalize y[t-1]
    if (t > 0 && tid < 4) {
        int b = b0 + tid;
        const float* yp = y_part + (size_t)b * 8;
        float yv = fcb[t - 1];
#pragma unroll
        for (int p = 0; p < 8; ++p) yv += yp[p];
        y_st[b] = yv;
        out_y[b * NT + (t - 1)] = yv;
    }
    __syncthreads();

    // scores: 24 row-tiles (4 b x 6) over 8 waves x 3 iters
    {
        const float scale_c = 0.044194173824159216f;  // 1/sqrt(512)
        float va_l[8];
#pragma unroll
        for (int nt = 0; nt < 8; ++nt) va_l[nt] = Va[(nt * 16 + ln) * NT + t];
#pragma unroll
        for (int ti = 0; ti < 3; ++ti) {
            int tau = wave + ti * 8;
            int bl = tau / 6, r0 = (tau % 6) * 16;
            const unsigned short* Hrow = Hbf + ((size_t)(b0 + bl) * NL + r0 + ln) * ND;
            f32x4 acc[8];
#pragma unroll
            for (int nt = 0; nt < 8; ++nt) acc[nt] = zero;
#pragma unroll
            for (int kc = 0; kc < 4; ++kc) {
                int d0 = kc * 32 + kg * 8;
                bf16x8 a = *(const bf16x8*)(Hrow + d0);
#pragma unroll
                for (int nt = 0; nt < 8; ++nt) {
                    bf16x8 bb = *(const bf16x8*)&Ws[(nt * 16 + ln) * 136 + d0];
                    acc[nt] = __builtin_amdgcn_mfma_f32_16x16x32_bf16(a, bb, acc[nt], 0, 0, 0);
                }
            }
#pragma unroll
            for (int r = 0; r < 4; ++r) {
                float s = 0.f;
#pragma unroll
                for (int nt = 0; nt < 8; ++nt) {
                    float pre = acc[nt][r] + cua_s4[bl][nt * 16 + ln];
                    s += va_l[nt] * fast_tanh(pre);
                }
#pragma unroll
                for (int off = 1; off < 16; off <<= 1) s += __shfl_xor(s, off);
                if (ln == 0) sc4[bl][r0 + kg * 4 + r] = s * scale_c;
            }
        }
    }
    __syncthreads();

    // softmax (wave w -> batch w, w<4)
    if (wave < 4) {
        float s0 = sc4[wave][lane];
        float s1 = (lane < 32) ? sc4[wave][64 + lane] : -1e30f;
        float m = fmaxf(s0, s1);
#pragma unroll
        for (int off = 32; off; off >>= 1) m = fmaxf(m, __shfl_xor(m, off));
        float p0 = fast_exp(s0 - m);
        float p1 = (lane < 32) ? fast_exp(s1 - m) : 0.f;
        float ssum = p0 + p1;
#pragma unroll
        for (int off = 32; off; off >>= 1) ssum += __shfl_xor(ssum, off);
        float inv = __builtin_amdgcn_rcpf(ssum);
        sc4[wave][lane] = p0 * inv;
        if (lane < 32) sc4[wave][64 + lane] = p1 * inv;
    }
    __syncthreads();

    // context: thread -> (bl, lg, dc); 8 l-groups x 12 l; vector bf16x8 reads
    {
        int bl = tid >> 7, r7 = tid & 127;
        int lg = r7 >> 4, dc = r7 & 15;
        int d0 = dc * 8;
        const unsigned short* Hb = Hbf + (size_t)(b0 + bl) * NL * ND;
        float a8[8] = {0, 0, 0, 0, 0, 0, 0, 0};
#pragma unroll
        for (int i = 0; i < 12; ++i) {
            int l = lg * 12 + i;
            bf16x8 hv = *(const bf16x8*)(Hb + (size_t)l * ND + d0);
            float w = sc4[bl][l];
#pragma unroll
            for (int j = 0; j < 8; ++j) a8[j] += w * b2f((unsigned short)hv[j]);
        }
#pragma unroll
        for (int j = 0; j < 8; ++j) red[bl][lg][d0 + j] = a8[j];
    }
    __syncthreads();
    {
        int bl = tid >> 7, dd = tid & 127;
        float accd = 0.f;
#pragma unroll
        for (int g = 0; g < 8; ++g) accd += red[bl][g][dd];
        Ab[(size_t)(b0 + bl) * NK + dd] = f2b(accd);
    }
}

// ---------------------------------------------------------------- fused gates GEMM + cell (M=64)
// grid (16, 8) x 512 thr: block = 64 rows x 64-s slice across 4 gates (256 cols).
// B direct from global; gs LDS 68 KB for epilogue redistribution (reused as cs).
__global__ __launch_bounds__(512) void k_gates_cell(
        const unsigned short* __restrict__ Ab,   // read: [ht | h] for step t
        unsigned short* __restrict__ AbN,        // write: h for step t+1
        const unsigned short* __restrict__ Wg,   // [t][kb][n][64]
        const float* __restrict__ bias,
        const float* __restrict__ Wy,
        const float* __restrict__ fcw,
        const float* __restrict__ Ua,
        const float* __restrict__ y_st,
        float* __restrict__ c,
        float* __restrict__ out_h,
        float* __restrict__ y_part,
        float* __restrict__ cua_part,
        int t) {
    __shared__ __align__(16) float gs[4 * 64 * 68];   // 69.6 KB
    int tid = threadIdx.x;
    int lane = tid & 63, wave = tid >> 6;
    int ln = lane & 15, kg = lane >> 4;
    int m0 = blockIdx.x * 64, n0 = blockIdx.y;
    int g = wave >> 1, hf = wave & 1;
    int cb = g * NHS + n0 * 64 + hf * 32;

    f32x4 zero = {0.f, 0.f, 0.f, 0.f};
    f32x4 acc[4][2];
#pragma unroll
    for (int rt = 0; rt < 4; ++rt)
#pragma unroll
        for (int nt = 0; nt < 2; ++nt) acc[rt][nt] = zero;

    for (int kb = 0; kb < 10; ++kb) {
        const unsigned short* Wkb = Wg + ((size_t)(t * 10 + kb) * NG4) * 64;
#pragma unroll
        for (int kc = 0; kc < 2; ++kc) {
            int dk = kb * 64 + kc * 32 + kg * 8;
            bf16x8 a0 = *(const bf16x8*)(Ab + (size_t)(m0 + ln) * NK + dk);
            bf16x8 a1 = *(const bf16x8*)(Ab + (size_t)(m0 + 16 + ln) * NK + dk);
            bf16x8 a2 = *(const bf16x8*)(Ab + (size_t)(m0 + 32 + ln) * NK + dk);
            bf16x8 a3 = *(const bf16x8*)(Ab + (size_t)(m0 + 48 + ln) * NK + dk);
#pragma unroll
            for (int nt = 0; nt < 2; ++nt) {
                bf16x8 bb = *(const bf16x8*)(Wkb
                    + (size_t)(cb + nt * 16 + ln) * 64 + kc * 32 + kg * 8);
                acc[0][nt] = __builtin_amdgcn_mfma_f32_16x16x32_bf16(a0, bb, acc[0][nt], 0, 0, 0);
                acc[1][nt] = __builtin_amdgcn_mfma_f32_16x16x32_bf16(a1, bb, acc[1][nt], 0, 0, 0);
                acc[2][nt] = __builtin_amdgcn_mfma_f32_16x16x32_bf16(a2, bb, acc[2][nt], 0, 0, 0);
                acc[3][nt] = __builtin_amdgcn_mfma_f32_16x16x32_bf16(a3, bb, acc[3][nt], 0, 0, 0);
            }
        }
    }
    // scatter: gs[g][row][s_loc]
#pragma unroll
    for (int rt = 0; rt < 4; ++rt)
#pragma unroll
        for (int nt = 0; nt < 2; ++nt)
#pragma unroll
            for (int r = 0; r < 4; ++r)
                gs[(size_t)(g * 64 + rt * 16 + kg * 4 + r) * 68 + hf * 32 + nt * 16 + ln]
                    = acc[rt][nt][r];
    __syncthreads();

    // cell update: thread -> s_loc (64), wave -> 8 rows
    int s_loc = tid & 63;
    int s_glob = n0 * 64 + s_loc;
    float bi0 = bias[t * NG4 + s_glob];
    float bi1 = bias[t * NG4 + NHS + s_glob];
    float bi2 = bias[t * NG4 + 2 * NHS + s_glob];
    float bi3 = bias[t * NG4 + 3 * NHS + s_glob];
    float wy0 = Wy[t * NG4 + s_glob];
    float wy1 = Wy[t * NG4 + NHS + s_glob];
    float wy2 = Wy[t * NG4 + 2 * NHS + s_glob];
    float wy3 = Wy[t * NG4 + 3 * NHS + s_glob];
    float fw  = fcw[t * NHS + s_glob];
    float prow[8];
#pragma unroll
    for (int i = 0; i < 8; ++i) {
        int row = wave * 8 + i;
        int b = m0 + row;
        float yp = y_st[b];
        float gi  = gs[(size_t)(0 * 64 + row) * 68 + s_loc] + bi0 + yp * wy0;
        float gfv = gs[(size_t)(1 * 64 + row) * 68 + s_loc] + bi1 + yp * wy1;
        float gg2 = gs[(size_t)(2 * 64 + row) * 68 + s_loc] + bi2 + yp * wy2;
        float go  = gs[(size_t)(3 * 64 + row) * 68 + s_loc] + bi3 + yp * wy3;
        float iv = fast_sigmoid(gi);
        float fv = fast_sigmoid(gfv);
        float gv = fast_tanh(gg2);
        float ov = fast_sigmoid(go);
        float cn = fv * c[(size_t)b * NHS + s_glob] + iv * gv;
        float hn = ov * fast_tanh(cn);
        c[(size_t)b * NHS + s_glob] = cn;
        gs[(size_t)(0 * 64 + row) * 68 + s_loc] = cn;   // reuse gate-i slot as cs
        AbN[(size_t)b * NK + ND + s_glob] = f2b(hn);
        out_h[(size_t)b * (NT * NHS) + t * NHS + s_glob] = hn;
        prow[i] = hn * fw;
    }
#pragma unroll
    for (int i = 0; i < 8; ++i) {
        float v = prow[i];
#pragma unroll
        for (int off = 32; off; off >>= 1) v += __shfl_xor(v, off);
        if (lane == 0) y_part[(size_t)(m0 + wave * 8 + i) * 8 + n0] = v;
    }
    __syncthreads();

    // cua partial for t+1 over this block's 64 c-cols (cs = gs[0])
    if (t + 1 < NT) {
        int n = tid & 127, bg = tid >> 7;   // 4 groups x 16 rows
        float a16[16];
#pragma unroll
        for (int i = 0; i < 16; ++i) a16[i] = 0.f;
        for (int k = 0; k < 64; ++k) {
            float ua = Ua[(size_t)(n0 * 64 + k) * (NT * NN) + (t + 1) * NN + n];
#pragma unroll
            for (int i = 0; i < 16; ++i)
                a16[i] += gs[(size_t)(bg * 16 + i) * 68 + k] * ua;
        }
#pragma unroll
        for (int i = 0; i < 16; ++i)
            cua_part[((size_t)(m0 + bg * 16 + i) * 8 + n0) * 128 + n] = a16[i];
    }
}

// ---------------------------------------------------------------- final y (t = NT-1)
__global__ __launch_bounds__(256) void k_yfin(const float* __restrict__ y_part,
                                              const float* __restrict__ fcb,
                                              float* __restrict__ out_y) {
    int b = blockIdx.x * 256 + threadIdx.x;
    if (b < NB) {
        const float* yp = y_part + (size_t)b * 8;
        float yv = fcb[NT - 1];
#pragma unroll
        for (int p = 0; p < 8; ++p) yv += yp[p];
        out_y[b * NT + (NT - 1)] = yv;
    }
}

// ---------------------------------------------------------------- launcher
extern "C" void kernel_launch(void* const* d_in, const int* in_sizes, int n_in,
                              void* d_out, int out_size, void* d_ws, size_t ws_size,
                              hipStream_t stream) {
    (void)in_sizes; (void)n_in; (void)out_size; (void)ws_size;
    const float* H    = (const float*)d_in[0];
    const float* y0   = (const float*)d_in[1];
    const float* emb  = (const float*)d_in[2];
    const float* Wa   = (const float*)d_in[4];
    const float* Ua   = (const float*)d_in[5];
    const float* ba   = (const float*)d_in[6];
    const float* Va   = (const float*)d_in[7];
    const float* W    = (const float*)d_in[8];
    const float* U    = (const float*)d_in[9];
    const float* bias = (const float*)d_in[10];
    const float* Wy   = (const float*)d_in[11];
    const float* fcw  = (const float*)d_in[12];
    const float* fcb  = (const float*)d_in[13];

    float* out_y = (float*)d_out;              // (B, T)
    float* out_h = out_y + NB * NT;            // (B, T, HS)

    float* ws       = (float*)d_ws;
    float* c_st     = ws;                                   // B*HS
    float* y_st     = c_st + NB * NHS;                      // B
    float* y_part   = y_st + NB;                            // B*8
    float* cua_part = y_part + NB * 8;                      // B*8*128
    unsigned short* Hbf = (unsigned short*)(cua_part + NB * 8 * 128);  // BL*D
    unsigned short* Wab = Hbf + (size_t)BL * ND;            // T*N*D
    unsigned short* Ab0 = Wab + (size_t)NT * NN * ND;       // B*640
    unsigned short* Ab1 = Ab0 + (size_t)NB * NK;            // B*640
    unsigned short* Wg  = Ab1 + (size_t)NB * NK;            // T*10*2048*64

    hipLaunchKernelGGL(k_init, dim3((NB * NHS) / 256), dim3(256), 0, stream,
                       emb, y0, c_st, Ab0, y_st);
    hipLaunchKernelGGL(k_prep, dim3(BL * ND / (256 * 8)), dim3(256), 0, stream, H, Hbf);
    hipLaunchKernelGGL(k_prepwa, dim3(NT * NN), dim3(128), 0, stream, Wa, Wab);
    hipLaunchKernelGGL(k_prepw, dim3(32, 10, 24), dim3(256), 0, stream, W, U, Wg);
    hipLaunchKernelGGL(k_cua0, dim3(64, 8), dim3(256), 0, stream, c_st, Ua, cua_part);

    for (int t = 0; t < NT; ++t) {
        unsigned short* Ab  = (t & 1) ? Ab1 : Ab0;
        unsigned short* AbN = (t & 1) ? Ab0 : Ab1;
        hipLaunchKernelGGL(k_attn4, dim3(NB / 4), dim3(512), 0, stream,
                           Hbf, Wab, Va, ba, cua_part, fcb, y_part, y_st, out_y, Ab, t);
        hipLaunchKernelGGL(k_gates_cell, dim3(16, 8), dim3(512), 0, stream,
                           Ab, AbN, Wg, bias, Wy, fcw, Ua, y_st, c_st,
                           out_h, y_part, cua_part, t);
    }
    hipLaunchKernelGGL(k_yfin, dim3(NB / 256), dim3(256), 0, stream, y_part, fcb, out_y);
}